// Round 9
// baseline (235.768 us; speedup 1.0000x reference)
//
#include <hip/hip_runtime.h>
#include <math.h>

#define NQ 4
#define NL 2

typedef __attribute__((ext_vector_type(8))) short short8v;  // 8 x bf16 (4 VGPRs)
typedef __attribute__((ext_vector_type(4))) float f32x4;

__device__ inline unsigned short f2bf(float x){
    unsigned u = __float_as_uint(x);
    u += 0x7FFFu + ((u >> 16) & 1u);          // RNE
    return (unsigned short)(u >> 16);
}
__device__ inline float bf2f(unsigned short h){
    return __uint_as_float(((unsigned)h) << 16);
}
// staging-path split (cold path, once per block)
__device__ inline void split8(const float* x, short8v& hi, short8v& lo){
    #pragma unroll
    for (int e = 0; e < 8; ++e){
        unsigned short h = f2bf(x[e]);
        hi[e] = (short)h;
        lo[e] = (short)f2bf(x[e] - bf2f(h));
    }
}
// legacy hot-path split (kept for the fused fallback kernel)
#define PK(i, val) { unsigned short h_ = f2bf(val); hi[i] = (short)h_; lo[i] = (short)f2bf((val) - bf2f(h_)); }
__device__ inline void pack8(float4 a, float4 b, short8v& hi, short8v& lo){
    PK(0, a.x) PK(1, a.y) PK(2, a.z) PK(3, a.w)
    PK(4, b.x) PK(5, b.y) PK(6, b.z) PK(7, b.w)
}
#undef PK

// hot-path split via v_cvt_pk_bf16_f32 (RNE, 2 f32 -> packed 2xbf16/instr).
__device__ inline void pack8_cvt(float4 a, float4 b, short8v& hi, short8v& lo){
    unsigned h0, h1, h2, h3;
    asm("v_cvt_pk_bf16_f32 %0, %1, %2" : "=v"(h0) : "v"(a.x), "v"(a.y));
    asm("v_cvt_pk_bf16_f32 %0, %1, %2" : "=v"(h1) : "v"(a.z), "v"(a.w));
    asm("v_cvt_pk_bf16_f32 %0, %1, %2" : "=v"(h2) : "v"(b.x), "v"(b.y));
    asm("v_cvt_pk_bf16_f32 %0, %1, %2" : "=v"(h3) : "v"(b.z), "v"(b.w));
    float r0 = a.x - __uint_as_float(h0 << 16);
    float r1 = a.y - __uint_as_float(h0 & 0xFFFF0000u);
    float r2 = a.z - __uint_as_float(h1 << 16);
    float r3 = a.w - __uint_as_float(h1 & 0xFFFF0000u);
    float r4 = b.x - __uint_as_float(h2 << 16);
    float r5 = b.y - __uint_as_float(h2 & 0xFFFF0000u);
    float r6 = b.z - __uint_as_float(h3 << 16);
    float r7 = b.w - __uint_as_float(h3 & 0xFFFF0000u);
    unsigned l0, l1, l2, l3;
    asm("v_cvt_pk_bf16_f32 %0, %1, %2" : "=v"(l0) : "v"(r0), "v"(r1));
    asm("v_cvt_pk_bf16_f32 %0, %1, %2" : "=v"(l1) : "v"(r2), "v"(r3));
    asm("v_cvt_pk_bf16_f32 %0, %1, %2" : "=v"(l2) : "v"(r4), "v"(r5));
    asm("v_cvt_pk_bf16_f32 %0, %1, %2" : "=v"(l3) : "v"(r6), "v"(r7));
    union { unsigned u[4]; short8v v; } H, L;
    H.u[0]=h0; H.u[1]=h1; H.u[2]=h2; H.u[3]=h3;
    L.u[0]=l0; L.u[1]=l1; L.u[2]=l2; L.u[3]=l3;
    hi = H.v; lo = L.v;
}

// ---------------------------------------------------------------------------
// Kernel 1: precompute A = Re(M^dagger D M)  (unchanged, verified)
// ---------------------------------------------------------------------------
__global__ void qnn_precompute_A(const float* __restrict__ qw, float* __restrict__ A)
{
    __shared__ float Mre[16][16];
    __shared__ float Mim[16][16];
    int t = threadIdx.x;
    if (t < 16) {
        int j = t;
        float re[16], im[16];
        for (int b = 0; b < 16; ++b) { re[b] = (b == j) ? 1.f : 0.f; im[b] = 0.f; }
        for (int l = 0; l < NL; ++l) {
            for (int i = 0; i < NQ; ++i) {
                float phi   = qw[(l*NQ + i)*3 + 0];
                float theta = qw[(l*NQ + i)*3 + 1];
                float omega = qw[(l*NQ + i)*3 + 2];
                float ct, st; sincosf(0.5f*theta, &st, &ct);
                float ap = 0.5f*(phi + omega);
                float am = 0.5f*(phi - omega);
                float cap, sap, cam, sam;
                sincosf(ap, &sap, &cap);
                sincosf(am, &sam, &cam);
                float u00r =  cap*ct, u00i = -sap*ct;
                float u01r = -cam*st, u01i = -sam*st;
                float u10r =  cam*st, u10i = -sam*st;
                float u11r =  cap*ct, u11i =  sap*ct;
                int mask = 1 << (3 - i);
                for (int b = 0; b < 16; ++b) {
                    if (b & mask) continue;
                    int b1 = b | mask;
                    float a0r = re[b],  a0i = im[b];
                    float a1r = re[b1], a1i = im[b1];
                    re[b]  = u00r*a0r - u00i*a0i + u01r*a1r - u01i*a1i;
                    im[b]  = u00r*a0i + u00i*a0r + u01r*a1i + u01i*a1r;
                    re[b1] = u10r*a0r - u10i*a0i + u11r*a1r - u11i*a1i;
                    im[b1] = u10r*a0i + u10i*a0r + u11r*a1i + u11i*a1r;
                }
            }
            for (int b = 0; b < 16; ++b) {
                float sgn = 1.f;
                if ((b & 0xC) == 0xC) sgn = -sgn;
                if ((b & 0x6) == 0x6) sgn = -sgn;
                if ((b & 0x3) == 0x3) sgn = -sgn;
                re[b] *= sgn; im[b] *= sgn;
            }
        }
        for (int b = 0; b < 16; ++b) { Mre[j][b] = re[b]; Mim[j][b] = im[b]; }
    }
    __syncthreads();
    {
        int j = t >> 4, k = t & 15;
        float s = 0.f;
        #pragma unroll
        for (int b = 0; b < 16; ++b) {
            float sg = (b & 8) ? -1.f : 1.f;
            s += sg * (Mre[j][b]*Mre[k][b] + Mim[j][b]*Mim[k][b]);
        }
        A[j*16 + k] = s;
    }
}

// ---------------------------------------------------------------------------
// shared helpers
// ---------------------------------------------------------------------------
__device__ inline void po_update(float (&po)[4][4], const f32x4& cc, const float4& w2){
    #pragma unroll
    for (int r = 0; r < 4; ++r){
        float h = fmaxf(cc[r], 0.f);
        po[r][0] = fmaf(h, w2.x, po[r][0]);
        po[r][1] = fmaf(h, w2.y, po[r][1]);
        po[r][2] = fmaf(h, w2.z, po[r][2]);
        po[r][3] = fmaf(h, w2.w, po[r][3]);
    }
}
__device__ inline void po_updateB(float (&po)[4][4], const f32x4& cc, const float4& w2, float bb){
    #pragma unroll
    for (int r = 0; r < 4; ++r){
        float h = fmaxf(cc[r] + bb, 0.f);
        po[r][0] = fmaf(h, w2.x, po[r][0]);
        po[r][1] = fmaf(h, w2.y, po[r][1]);
        po[r][2] = fmaf(h, w2.z, po[r][2]);
        po[r][3] = fmaf(h, w2.w, po[r][3]);
    }
}
__device__ inline void reduce_po(float (&po)[4][4]){
    #pragma unroll
    for (int r = 0; r < 4; ++r)
        #pragma unroll
        for (int o = 0; o < 4; ++o){
            float v = po[r][o];
            v += __shfl_xor(v, 1);
            v += __shfl_xor(v, 2);
            v += __shfl_xor(v, 4);
            v += __shfl_xor(v, 8);
            po[r][o] = v;
        }
}
__device__ inline float4 pick_row(const float (&po)[4][4], int c){
    float4 v;
    if      (c == 0) v = make_float4(po[0][0], po[0][1], po[0][2], po[0][3]);
    else if (c == 1) v = make_float4(po[1][0], po[1][1], po[1][2], po[1][3]);
    else if (c == 2) v = make_float4(po[2][0], po[2][1], po[2][2], po[2][3]);
    else             v = make_float4(po[3][0], po[3][1], po[3][2], po[3][3]);
    return v;
}

#define STEP3(ACC, BH, BL, AH, AL)                                          \
    ACC = __builtin_amdgcn_mfma_f32_16x16x32_bf16(AH, BH, ACC, 0, 0, 0);    \
    ACC = __builtin_amdgcn_mfma_f32_16x16x32_bf16(AH, BL, ACC, 0, 0, 0);    \
    ACC = __builtin_amdgcn_mfma_f32_16x16x32_bf16(AL, BH, ACC, 0, 0, 0);

// ---------------------------------------------------------------------------
// Kernel 2a: feats only. R9 change vs R8: __launch_bounds__(256, 8).
// R8 landed at VGPR=60, zero spill (WRITE_SIZE == real output) but only 33%
// occupancy -- the (256,4) bound capped residency at 4 blocks/CU while the
// allocation fits the 64-reg / 8-waves-per-SIMD operating point. LDS
// (22.5KB/block) allows 7 blocks/CU = 87% occupancy ceiling. Same code,
// 2.6x more TLP to cover ds_read latency + the 4-deep shfl reduce chains.
// R6/R7 A/B already showed occupancy is the binding resource here.
// ---------------------------------------------------------------------------
__global__ __launch_bounds__(256, 8) void qnn_feats(
    const float* __restrict__ text, const float* __restrict__ image,
    const float* __restrict__ tW1, const float* __restrict__ tb1,
    const float* __restrict__ tW2,
    const float* __restrict__ iW1, const float* __restrict__ ib1,
    const float* __restrict__ iW2,
    float* __restrict__ featsOut, int B)
{
    __shared__ short8v WimgH[4][2][64];   // [nt][ks][lane]  8 KB
    __shared__ short8v WimgL[4][2][64];   //                 8 KB
    __shared__ short8v WtxtH[2][64];      //                 2 KB
    __shared__ short8v WtxtL[2][64];      //                 2 KB
    __shared__ float4  W2s[96];           // iW2 rows 0..63, tW2 rows 64..95 (1.5 KB)
    __shared__ float   Bs[96];            // ib1 0..63, tb1 64..95 (384 B)

    const int t    = threadIdx.x;
    const int lane = t & 63;
    const int wv   = t >> 6;
    const int g    = lane >> 4;
    const int c    = lane & 15;
    const long long blockBase = (long long)blockIdx.x * 256;
    const long long base = blockBase + wv*64 + c;

    // ---------- cooperative staging (once per block) ------------------------
    #pragma unroll
    for (int s = t; s < 512; s += 256){
        int nt = s >> 7, ks = (s >> 6) & 1, ln = s & 63;
        int gg = ln >> 4, cc_ = ln & 15;
        float x[8];
        #pragma unroll
        for (int e = 0; e < 8; ++e){
            int k = ks*32 + 8*gg + e;
            x[e] = (k < 48) ? iW1[k*64 + nt*16 + cc_] : 0.f;
        }
        short8v h, l; split8(x, h, l);
        WimgH[nt][ks][ln] = h;
        WimgL[nt][ks][ln] = l;
    }
    if (t < 128){
        int nt = t >> 6, ln = t & 63;
        int gg = ln >> 4, cc_ = ln & 15;
        float x[8];
        #pragma unroll
        for (int e = 0; e < 8; ++e){
            int k = 8*gg + e;
            x[e] = (k < 16) ? tW1[k*32 + nt*16 + cc_] : 0.f;
        }
        short8v h, l; split8(x, h, l);
        WtxtH[nt][ln] = h;
        WtxtL[nt][ln] = l;
    }
    if (t < 96){
        W2s[t] = (t < 64) ? ((const float4*)iW2)[t] : ((const float4*)tW2)[t - 64];
        Bs[t]  = (t < 64) ? ib1[t] : tb1[t - 64];
    }
    __syncthreads();

    const float4 z = make_float4(0.f, 0.f, 0.f, 0.f);

    // ---------------- prologue: load tile 0 into cur ------------------------
    float4 c0, c1, c2, c3, c4, c5;
    {
        long long m = base; if (m >= B) m = B - 1;
        const float* irow = image + m*48;
        const float* trow = text  + m*16;
        c0 = *(const float4*)(irow + 8*g);
        c1 = *(const float4*)(irow + 8*g + 4);
        c2 = z; c3 = z; c4 = z; c5 = z;
        if (g < 2){
            c2 = *(const float4*)(irow + 32 + 8*g);
            c3 = *(const float4*)(irow + 36 + 8*g);
            c4 = *(const float4*)(trow + 8*g);
            c5 = *(const float4*)(trow + 8*g + 4);
        }
    }

    float4 n0 = z, n1 = z, n2 = z, n3 = z, n4 = z, n5 = z;

    // ---------------- main loop: 4 M-tiles, prefetch depth 1 ----------------
    #pragma unroll 1
    for (int ms = 0; ms < 4; ++ms){
        if (ms < 3){
            long long m = base + (ms + 1)*16; if (m >= B) m = B - 1;
            const float* irow = image + m*48;
            const float* trow = text  + m*16;
            n0 = *(const float4*)(irow + 8*g);
            n1 = *(const float4*)(irow + 8*g + 4);
            if (g < 2){
                n2 = *(const float4*)(irow + 32 + 8*g);
                n3 = *(const float4*)(irow + 36 + 8*g);
                n4 = *(const float4*)(trow + 8*g);
                n5 = *(const float4*)(trow + 8*g + 4);
            }
        }

        short8v A0h, A0l, A1h, A1l, ATh, ATl;
        pack8_cvt(c0, c1, A0h, A0l);
        pack8_cvt(c2, c3, A1h, A1l);
        pack8_cvt(c4, c5, ATh, ATl);

        f32x4 a0 = { 0.f, 0.f, 0.f, 0.f };
        f32x4 a1 = { 0.f, 0.f, 0.f, 0.f };
        f32x4 a2 = { 0.f, 0.f, 0.f, 0.f };
        f32x4 a3 = { 0.f, 0.f, 0.f, 0.f };
        f32x4 a4 = { 0.f, 0.f, 0.f, 0.f };
        f32x4 a5 = { 0.f, 0.f, 0.f, 0.f };

        // ---- phase 1: image k 0..31 ----
        { short8v bh = WimgH[0][0][lane], bl = WimgL[0][0][lane]; STEP3(a0, bh, bl, A0h, A0l) }
        { short8v bh = WimgH[1][0][lane], bl = WimgL[1][0][lane]; STEP3(a1, bh, bl, A0h, A0l) }
        { short8v bh = WimgH[2][0][lane], bl = WimgL[2][0][lane]; STEP3(a2, bh, bl, A0h, A0l) }
        { short8v bh = WimgH[3][0][lane], bl = WimgL[3][0][lane]; STEP3(a3, bh, bl, A0h, A0l) }
        __builtin_amdgcn_sched_barrier(0);

        // ---- phase 2: image k 32..47 (zero-padded to 64) ----
        { short8v bh = WimgH[0][1][lane], bl = WimgL[0][1][lane]; STEP3(a0, bh, bl, A1h, A1l) }
        { short8v bh = WimgH[1][1][lane], bl = WimgL[1][1][lane]; STEP3(a1, bh, bl, A1h, A1l) }
        { short8v bh = WimgH[2][1][lane], bl = WimgL[2][1][lane]; STEP3(a2, bh, bl, A1h, A1l) }
        { short8v bh = WimgH[3][1][lane], bl = WimgL[3][1][lane]; STEP3(a3, bh, bl, A1h, A1l) }
        __builtin_amdgcn_sched_barrier(0);

        // ---- phase 3: text k 0..15 (zero-padded to 32) ----
        { short8v bh = WtxtH[0][lane], bl = WtxtL[0][lane]; STEP3(a4, bh, bl, ATh, ATl) }
        { short8v bh = WtxtH[1][lane], bl = WtxtL[1][lane]; STEP3(a5, bh, bl, ATh, ATl) }

        // ---- epilogue: bias + relu + layer-2 (operands from LDS) -----------
        float po[4][4];
        #pragma unroll
        for (int r = 0; r < 4; ++r)
            #pragma unroll
            for (int o = 0; o < 4; ++o) po[r][o] = 0.f;

        { float4 w2 = W2s[c];      po_updateB(po, a0, w2, Bs[c]); }
        { float4 w2 = W2s[16+c];   po_updateB(po, a1, w2, Bs[16+c]); }
        { float4 w2 = W2s[32+c];   po_updateB(po, a2, w2, Bs[32+c]); }
        { float4 w2 = W2s[48+c];   po_updateB(po, a3, w2, Bs[48+c]); }
        { float4 w2 = W2s[64+c];   po_updateB(po, a4, w2, Bs[64+c]); }
        { float4 w2 = W2s[80+c];   po_updateB(po, a5, w2, Bs[80+c]); }

        reduce_po(po);
        if (c < 4){
            long long sIdx = blockBase + wv*64 + ms*16 + 4*g + c;
            if (sIdx < B)
                ((float4*)featsOut)[sIdx] = pick_row(po, c);
        }
        __builtin_amdgcn_sched_barrier(0);

        c0 = n0; c1 = n1; c2 = n2; c3 = n3; c4 = n4; c5 = n5;
    }
}

// ---------------------------------------------------------------------------
// Kernel 2b: quantum quadratic form + head, 1 thread/sample, lean registers.
// ---------------------------------------------------------------------------
__global__ __launch_bounds__(256, 8) void qnn_tail(
    const float* __restrict__ feats,
    const float* __restrict__ tb2, const float* __restrict__ ib2,
    const float* __restrict__ Aq,
    const float* __restrict__ cW1, const float* __restrict__ cb1,
    const float* __restrict__ cW2, const float* __restrict__ cb2,
    float* __restrict__ out, int B)
{
    __shared__ float As[256];
    const int t = threadIdx.x;
    As[t] = Aq[t];
    __syncthreads();

    long long samp = (long long)blockIdx.x * 256 + t;
    if (samp >= B) return;

    float4 f4 = ((const float4*)feats)[samp];
    float acc[4];
    acc[0] = tb2[0] + ib2[0] + f4.x;
    acc[1] = tb2[1] + ib2[1] + f4.y;
    acc[2] = tb2[2] + ib2[2] + f4.z;
    acc[3] = tb2[3] + ib2[3] + f4.w;

    float cth[4], sth[4];
    #pragma unroll
    for (int i = 0; i < 4; ++i){
        float f = acc[i] * 0.25f;
        __sincosf(f, &sth[i], &cth[i]);
    }
    float p01[4] = { cth[0]*cth[1], cth[0]*sth[1], sth[0]*cth[1], sth[0]*sth[1] };
    float p23[4] = { cth[2]*cth[3], cth[2]*sth[3], sth[2]*cth[3], sth[2]*sth[3] };
    float psi[16];
    #pragma unroll
    for (int x = 0; x < 4; ++x)
        #pragma unroll
        for (int y = 0; y < 4; ++y)
            psi[x*4+y] = p01[x] * p23[y];

    float q = 0.f;
    #pragma unroll
    for (int j = 0; j < 16; ++j){
        float row = 0.f;
        #pragma unroll
        for (int k = 0; k < 16; ++k) row = fmaf(As[j*16+k], psi[k], row);
        q = fmaf(psi[j], row, q);
    }

    float o0 = cb2[0], o1 = cb2[1];
    #pragma unroll
    for (int j = 0; j < 16; ++j){
        float h = fmaxf(fmaf(q, cW1[j], cb1[j]), 0.f);
        o0 = fmaf(h, cW2[j*2+0], o0);
        o1 = fmaf(h, cW2[j*2+1], o1);
    }
    float2* o2 = (float2*)out;
    o2[samp] = make_float2(o0, o1);
}

// ---------------------------------------------------------------------------
// Fallback: verified fused kernel (used only if workspace too small)
// ---------------------------------------------------------------------------
__global__ __launch_bounds__(256, 4) void qnn_fused(
    const float* __restrict__ text, const float* __restrict__ image,
    const float* __restrict__ tW1, const float* __restrict__ tb1,
    const float* __restrict__ tW2, const float* __restrict__ tb2,
    const float* __restrict__ iW1, const float* __restrict__ ib1,
    const float* __restrict__ iW2, const float* __restrict__ ib2,
    const float* __restrict__ A,
    const float* __restrict__ cW1, const float* __restrict__ cb1,
    const float* __restrict__ cW2, const float* __restrict__ cb2,
    float* __restrict__ out, int B)
{
    __shared__ short8v WimgH[4][2][64];
    __shared__ short8v WimgL[4][2][64];
    __shared__ short8v WtxtH[2][64];
    __shared__ short8v WtxtL[2][64];
    __shared__ float4  feats[256];

    const int t    = threadIdx.x;
    const int lane = t & 63;
    const int wv   = t >> 6;
    const int g    = lane >> 4;
    const int c    = lane & 15;
    const long long blockBase = (long long)blockIdx.x * 256;

    #pragma unroll
    for (int s = t; s < 512; s += 256){
        int nt = s >> 7, ks = (s >> 6) & 1, ln = s & 63;
        int gg = ln >> 4, cc_ = ln & 15;
        float x[8];
        #pragma unroll
        for (int e = 0; e < 8; ++e){
            int k = ks*32 + 8*gg + e;
            x[e] = (k < 48) ? iW1[k*64 + nt*16 + cc_] : 0.f;
        }
        short8v h, l; split8(x, h, l);
        WimgH[nt][ks][ln] = h;
        WimgL[nt][ks][ln] = l;
    }
    if (t < 128){
        int nt = t >> 6, ln = t & 63;
        int gg = ln >> 4, cc_ = ln & 15;
        float x[8];
        #pragma unroll
        for (int e = 0; e < 8; ++e){
            int k = 8*gg + e;
            x[e] = (k < 16) ? tW1[k*32 + nt*16 + cc_] : 0.f;
        }
        short8v h, l; split8(x, h, l);
        WtxtH[nt][ln] = h;
        WtxtL[nt][ln] = l;
    }
    __syncthreads();

    const float bI0 = ib1[c],      bI1 = ib1[16 + c];
    const float bI2 = ib1[32 + c], bI3 = ib1[48 + c];
    const float bT0 = tb1[c],      bT1 = tb1[16 + c];

    #pragma unroll 1
    for (int ms = 0; ms < 4; ++ms){
        long long m = blockBase + wv*64 + ms*16 + c;
        if (m >= B) m = B - 1;
        const float* irow = image + m*48;
        const float* trow = text  + m*16;

        const float4 z = make_float4(0.f, 0.f, 0.f, 0.f);
        float4 i0a = *(const float4*)(irow + 8*g);
        float4 i0b = *(const float4*)(irow + 8*g + 4);
        float4 i1a = z, i1b = z, t0a = z, t0b = z;
        if (g < 2){
            i1a = *(const float4*)(irow + 32 + 8*g);
            i1b = *(const float4*)(irow + 36 + 8*g);
            t0a = *(const float4*)(trow + 8*g);
            t0b = *(const float4*)(trow + 8*g + 4);
        }

        f32x4 a0 = { bI0, bI0, bI0, bI0 };
        f32x4 a1 = { bI1, bI1, bI1, bI1 };
        f32x4 a2 = { bI2, bI2, bI2, bI2 };
        f32x4 a3 = { bI3, bI3, bI3, bI3 };
        f32x4 a4 = { bT0, bT0, bT0, bT0 };
        f32x4 a5 = { bT1, bT1, bT1, bT1 };

        short8v Ah, Al;

        pack8(i0a, i0b, Ah, Al);
        { short8v bh = WimgH[0][0][lane], bl = WimgL[0][0][lane]; STEP3(a0, bh, bl, Ah, Al) }
        { short8v bh = WimgH[1][0][lane], bl = WimgL[1][0][lane]; STEP3(a1, bh, bl, Ah, Al) }
        { short8v bh = WimgH[2][0][lane], bl = WimgL[2][0][lane]; STEP3(a2, bh, bl, Ah, Al) }
        { short8v bh = WimgH[3][0][lane], bl = WimgL[3][0][lane]; STEP3(a3, bh, bl, Ah, Al) }
        __builtin_amdgcn_sched_barrier(0);

        pack8(i1a, i1b, Ah, Al);
        { short8v bh = WimgH[0][1][lane], bl = WimgL[0][1][lane]; STEP3(a0, bh, bl, Ah, Al) }
        { short8v bh = WimgH[1][1][lane], bl = WimgL[1][1][lane]; STEP3(a1, bh, bl, Ah, Al) }
        { short8v bh = WimgH[2][1][lane], bl = WimgL[2][1][lane]; STEP3(a2, bh, bl, Ah, Al) }
        { short8v bh = WimgH[3][1][lane], bl = WimgL[3][1][lane]; STEP3(a3, bh, bl, Ah, Al) }
        __builtin_amdgcn_sched_barrier(0);

        pack8(t0a, t0b, Ah, Al);
        { short8v bh = WtxtH[0][lane], bl = WtxtL[0][lane]; STEP3(a4, bh, bl, Ah, Al) }
        { short8v bh = WtxtH[1][lane], bl = WtxtL[1][lane]; STEP3(a5, bh, bl, Ah, Al) }
        __builtin_amdgcn_sched_barrier(0);

        float po[4][4];
        #pragma unroll
        for (int r = 0; r < 4; ++r)
            #pragma unroll
            for (int o = 0; o < 4; ++o) po[r][o] = 0.f;

        { float4 w2 = *(const float4*)(iW2 + (c)*4);      po_update(po, a0, w2); }
        { float4 w2 = *(const float4*)(iW2 + (16+c)*4);   po_update(po, a1, w2); }
        { float4 w2 = *(const float4*)(iW2 + (32+c)*4);   po_update(po, a2, w2); }
        { float4 w2 = *(const float4*)(iW2 + (48+c)*4);   po_update(po, a3, w2); }
        { float4 w2 = *(const float4*)(tW2 + (c)*4);      po_update(po, a4, w2); }
        { float4 w2 = *(const float4*)(tW2 + (16+c)*4);   po_update(po, a5, w2); }

        reduce_po(po);
        if (c < 4)
            feats[wv*64 + ms*16 + 4*g + c] = pick_row(po, c);
        __builtin_amdgcn_sched_barrier(0);
    }

    __syncthreads();

    long long samp = blockBase + t;
    if (samp < B){
        float4 f4 = feats[t];
        float acc[4];
        acc[0] = tb2[0] + ib2[0] + f4.x;
        acc[1] = tb2[1] + ib2[1] + f4.y;
        acc[2] = tb2[2] + ib2[2] + f4.z;
        acc[3] = tb2[3] + ib2[3] + f4.w;

        float cth[4], sth[4];
        #pragma unroll
        for (int i = 0; i < 4; ++i){
            float f = acc[i] * 0.25f;
            __sincosf(f, &sth[i], &cth[i]);
        }
        float p01[4] = { cth[0]*cth[1], cth[0]*sth[1], sth[0]*cth[1], sth[0]*sth[1] };
        float p23[4] = { cth[2]*cth[3], cth[2]*sth[3], sth[2]*cth[3], sth[2]*sth[3] };
        float psi[16];
        #pragma unroll
        for (int x = 0; x < 4; ++x)
            #pragma unroll
            for (int y = 0; y < 4; ++y)
                psi[x*4+y] = p01[x] * p23[y];

        float q = 0.f;
        #pragma unroll
        for (int j = 0; j < 16; ++j){
            float row = 0.f;
            #pragma unroll
            for (int k = 0; k < 16; ++k) row = fmaf(A[j*16+k], psi[k], row);
            q = fmaf(psi[j], row, q);
        }

        float o0 = cb2[0], o1 = cb2[1];
        #pragma unroll
        for (int j = 0; j < 16; ++j){
            float h = fmaxf(fmaf(q, cW1[j], cb1[j]), 0.f);
            o0 = fmaf(h, cW2[j*2+0], o0);
            o1 = fmaf(h, cW2[j*2+1], o1);
        }
        float2* o2 = (float2*)out;
        o2[samp] = make_float2(o0, o1);
    }
}

extern "C" void kernel_launch(void* const* d_in, const int* in_sizes, int n_in,
                              void* d_out, int out_size, void* d_ws, size_t ws_size,
                              hipStream_t stream)
{
    const float* text  = (const float*)d_in[0];
    const float* image = (const float*)d_in[1];
    const float* tW1   = (const float*)d_in[2];
    const float* tb1   = (const float*)d_in[3];
    const float* tW2   = (const float*)d_in[4];
    const float* tb2   = (const float*)d_in[5];
    const float* iW1   = (const float*)d_in[6];
    const float* ib1   = (const float*)d_in[7];
    const float* iW2   = (const float*)d_in[8];
    const float* ib2   = (const float*)d_in[9];
    const float* qw    = (const float*)d_in[10];
    const float* cW1   = (const float*)d_in[11];
    const float* cb1   = (const float*)d_in[12];
    const float* cW2   = (const float*)d_in[13];
    const float* cb2   = (const float*)d_in[14];

    float* A = (float*)d_ws;          // 256 floats
    int B = in_sizes[0] / 16;

    qnn_precompute_A<<<1, 256, 0, stream>>>(qw, A);

    int block = 256;
    int grid = (B + block - 1) / block;
    size_t need = 1024 + (size_t)B * 16;   // A (1 KB) + feats (B x float4)

    if (ws_size >= need){
        float* featsWs = (float*)((char*)d_ws + 1024);
        qnn_feats<<<grid, block, 0, stream>>>(
            text, image, tW1, tb1, tW2, iW1, ib1, iW2, featsWs, B);
        qnn_tail<<<grid, block, 0, stream>>>(
            featsWs, tb2, ib2, A, cW1, cb1, cW2, cb2, (float*)d_out, B);
    } else {
        qnn_fused<<<grid, block, 0, stream>>>(
            text, image, tW1, tb1, tW2, tb2, iW1, ib1, iW2, ib2,
            A, cW1, cb1, cW2, cb2, (float*)d_out, B);
    }
}

// Round 10
// 226.084 us; speedup vs baseline: 1.0428x; 1.0428x over previous
//
#include <hip/hip_runtime.h>
#include <math.h>

#define NQ 4
#define NL 2

typedef __attribute__((ext_vector_type(8))) short short8v;  // 8 x bf16 (4 VGPRs)
typedef __attribute__((ext_vector_type(4))) float f32x4;

__device__ inline unsigned short f2bf(float x){
    unsigned u = __float_as_uint(x);
    u += 0x7FFFu + ((u >> 16) & 1u);          // RNE
    return (unsigned short)(u >> 16);
}
__device__ inline float bf2f(unsigned short h){
    return __uint_as_float(((unsigned)h) << 16);
}
// staging-path split (cold path, once per block)
__device__ inline void split8(const float* x, short8v& hi, short8v& lo){
    #pragma unroll
    for (int e = 0; e < 8; ++e){
        unsigned short h = f2bf(x[e]);
        hi[e] = (short)h;
        lo[e] = (short)f2bf(x[e] - bf2f(h));
    }
}
// legacy hot-path split (kept for the fused fallback kernel)
#define PK(i, val) { unsigned short h_ = f2bf(val); hi[i] = (short)h_; lo[i] = (short)f2bf((val) - bf2f(h_)); }
__device__ inline void pack8(float4 a, float4 b, short8v& hi, short8v& lo){
    PK(0, a.x) PK(1, a.y) PK(2, a.z) PK(3, a.w)
    PK(4, b.x) PK(5, b.y) PK(6, b.z) PK(7, b.w)
}
#undef PK

// hot-path split via v_cvt_pk_bf16_f32 (RNE, 2 f32 -> packed 2xbf16/instr).
__device__ inline void pack8_cvt(float4 a, float4 b, short8v& hi, short8v& lo){
    unsigned h0, h1, h2, h3;
    asm("v_cvt_pk_bf16_f32 %0, %1, %2" : "=v"(h0) : "v"(a.x), "v"(a.y));
    asm("v_cvt_pk_bf16_f32 %0, %1, %2" : "=v"(h1) : "v"(a.z), "v"(a.w));
    asm("v_cvt_pk_bf16_f32 %0, %1, %2" : "=v"(h2) : "v"(b.x), "v"(b.y));
    asm("v_cvt_pk_bf16_f32 %0, %1, %2" : "=v"(h3) : "v"(b.z), "v"(b.w));
    float r0 = a.x - __uint_as_float(h0 << 16);
    float r1 = a.y - __uint_as_float(h0 & 0xFFFF0000u);
    float r2 = a.z - __uint_as_float(h1 << 16);
    float r3 = a.w - __uint_as_float(h1 & 0xFFFF0000u);
    float r4 = b.x - __uint_as_float(h2 << 16);
    float r5 = b.y - __uint_as_float(h2 & 0xFFFF0000u);
    float r6 = b.z - __uint_as_float(h3 << 16);
    float r7 = b.w - __uint_as_float(h3 & 0xFFFF0000u);
    unsigned l0, l1, l2, l3;
    asm("v_cvt_pk_bf16_f32 %0, %1, %2" : "=v"(l0) : "v"(r0), "v"(r1));
    asm("v_cvt_pk_bf16_f32 %0, %1, %2" : "=v"(l1) : "v"(r2), "v"(r3));
    asm("v_cvt_pk_bf16_f32 %0, %1, %2" : "=v"(l2) : "v"(r4), "v"(r5));
    asm("v_cvt_pk_bf16_f32 %0, %1, %2" : "=v"(l3) : "v"(r6), "v"(r7));
    union { unsigned u[4]; short8v v; } H, L;
    H.u[0]=h0; H.u[1]=h1; H.u[2]=h2; H.u[3]=h3;
    L.u[0]=l0; L.u[1]=l1; L.u[2]=l2; L.u[3]=l3;
    hi = H.v; lo = L.v;
}

// ---------------------------------------------------------------------------
// Kernel 1: precompute A = Re(M^dagger D M)  (unchanged, verified)
// ---------------------------------------------------------------------------
__global__ void qnn_precompute_A(const float* __restrict__ qw, float* __restrict__ A)
{
    __shared__ float Mre[16][16];
    __shared__ float Mim[16][16];
    int t = threadIdx.x;
    if (t < 16) {
        int j = t;
        float re[16], im[16];
        for (int b = 0; b < 16; ++b) { re[b] = (b == j) ? 1.f : 0.f; im[b] = 0.f; }
        for (int l = 0; l < NL; ++l) {
            for (int i = 0; i < NQ; ++i) {
                float phi   = qw[(l*NQ + i)*3 + 0];
                float theta = qw[(l*NQ + i)*3 + 1];
                float omega = qw[(l*NQ + i)*3 + 2];
                float ct, st; sincosf(0.5f*theta, &st, &ct);
                float ap = 0.5f*(phi + omega);
                float am = 0.5f*(phi - omega);
                float cap, sap, cam, sam;
                sincosf(ap, &sap, &cap);
                sincosf(am, &sam, &cam);
                float u00r =  cap*ct, u00i = -sap*ct;
                float u01r = -cam*st, u01i = -sam*st;
                float u10r =  cam*st, u10i = -sam*st;
                float u11r =  cap*ct, u11i =  sap*ct;
                int mask = 1 << (3 - i);
                for (int b = 0; b < 16; ++b) {
                    if (b & mask) continue;
                    int b1 = b | mask;
                    float a0r = re[b],  a0i = im[b];
                    float a1r = re[b1], a1i = im[b1];
                    re[b]  = u00r*a0r - u00i*a0i + u01r*a1r - u01i*a1i;
                    im[b]  = u00r*a0i + u00i*a0r + u01r*a1i + u01i*a1r;
                    re[b1] = u10r*a0r - u10i*a0i + u11r*a1r - u11i*a1i;
                    im[b1] = u10r*a0i + u10i*a0r + u11r*a1i + u11i*a1r;
                }
            }
            for (int b = 0; b < 16; ++b) {
                float sgn = 1.f;
                if ((b & 0xC) == 0xC) sgn = -sgn;
                if ((b & 0x6) == 0x6) sgn = -sgn;
                if ((b & 0x3) == 0x3) sgn = -sgn;
                re[b] *= sgn; im[b] *= sgn;
            }
        }
        for (int b = 0; b < 16; ++b) { Mre[j][b] = re[b]; Mim[j][b] = im[b]; }
    }
    __syncthreads();
    {
        int j = t >> 4, k = t & 15;
        float s = 0.f;
        #pragma unroll
        for (int b = 0; b < 16; ++b) {
            float sg = (b & 8) ? -1.f : 1.f;
            s += sg * (Mre[j][b]*Mre[k][b] + Mim[j][b]*Mim[k][b]);
        }
        A[j*16 + k] = s;
    }
}

// ---------------------------------------------------------------------------
// shared helpers
// ---------------------------------------------------------------------------
__device__ inline void po_update(float (&po)[4][4], const f32x4& cc, const float4& w2){
    #pragma unroll
    for (int r = 0; r < 4; ++r){
        float h = fmaxf(cc[r], 0.f);
        po[r][0] = fmaf(h, w2.x, po[r][0]);
        po[r][1] = fmaf(h, w2.y, po[r][1]);
        po[r][2] = fmaf(h, w2.z, po[r][2]);
        po[r][3] = fmaf(h, w2.w, po[r][3]);
    }
}
__device__ inline void po_updateB(float (&po)[4][4], const f32x4& cc, const float4& w2, float bb){
    #pragma unroll
    for (int r = 0; r < 4; ++r){
        float h = fmaxf(cc[r] + bb, 0.f);
        po[r][0] = fmaf(h, w2.x, po[r][0]);
        po[r][1] = fmaf(h, w2.y, po[r][1]);
        po[r][2] = fmaf(h, w2.z, po[r][2]);
        po[r][3] = fmaf(h, w2.w, po[r][3]);
    }
}

// ---- DPP rotation reduce within each 16-lane row (VALU only, NO LDS pipe) --
// R10 key change: __shfl_xor lowers to ds_swizzle_b32 (LDS pipe, per-CU
// shared) -- 256 swizzles + waits per M-tile per wave saturated the LDS pipe,
// which is why dur was invariant to occupancy (R6/R8/R9: 26-38% occ, all
// ~70us). row_ror DPP is a VALU data-path permute: v_add_f32 + dpp modifier.
// Rotation reduce: after +ror8,+ror4,+ror2,+ror1 every lane holds the 16-lane
// sum. dpp_ctrl: ROW_ROR|N = 0x120|N.
template<int CTRL>
__device__ inline float dpp_rot(float x){
    return __uint_as_float((unsigned)__builtin_amdgcn_update_dpp(
        0, (int)__float_as_uint(x), CTRL, 0xF, 0xF, true));
}
__device__ inline float row16_sum(float v){
    v += dpp_rot<0x128>(v);   // ror:8
    v += dpp_rot<0x124>(v);   // ror:4
    v += dpp_rot<0x122>(v);   // ror:2
    v += dpp_rot<0x121>(v);   // ror:1
    return v;
}
__device__ inline void reduce_po(float (&po)[4][4]){
    #pragma unroll
    for (int r = 0; r < 4; ++r)
        #pragma unroll
        for (int o = 0; o < 4; ++o)
            po[r][o] = row16_sum(po[r][o]);
}
__device__ inline float4 pick_row(const float (&po)[4][4], int c){
    float4 v;
    if      (c == 0) v = make_float4(po[0][0], po[0][1], po[0][2], po[0][3]);
    else if (c == 1) v = make_float4(po[1][0], po[1][1], po[1][2], po[1][3]);
    else if (c == 2) v = make_float4(po[2][0], po[2][1], po[2][2], po[2][3]);
    else             v = make_float4(po[3][0], po[3][1], po[3][2], po[3][3]);
    return v;
}

#define STEP3(ACC, BH, BL, AH, AL)                                          \
    ACC = __builtin_amdgcn_mfma_f32_16x16x32_bf16(AH, BH, ACC, 0, 0, 0);    \
    ACC = __builtin_amdgcn_mfma_f32_16x16x32_bf16(AH, BL, ACC, 0, 0, 0);    \
    ACC = __builtin_amdgcn_mfma_f32_16x16x32_bf16(AL, BH, ACC, 0, 0, 0);

// ---------------------------------------------------------------------------
// Kernel 2a: feats only. R10 = R8 config ((256,4), VGPR~60, zero spill) with
// ONE change: reduce_po now uses DPP row_ror rotation reduce instead of
// __shfl_xor/ds_swizzle. See reduce_po comment for the theory.
// ---------------------------------------------------------------------------
__global__ __launch_bounds__(256, 4) void qnn_feats(
    const float* __restrict__ text, const float* __restrict__ image,
    const float* __restrict__ tW1, const float* __restrict__ tb1,
    const float* __restrict__ tW2,
    const float* __restrict__ iW1, const float* __restrict__ ib1,
    const float* __restrict__ iW2,
    float* __restrict__ featsOut, int B)
{
    __shared__ short8v WimgH[4][2][64];   // [nt][ks][lane]  8 KB
    __shared__ short8v WimgL[4][2][64];   //                 8 KB
    __shared__ short8v WtxtH[2][64];      //                 2 KB
    __shared__ short8v WtxtL[2][64];      //                 2 KB
    __shared__ float4  W2s[96];           // iW2 rows 0..63, tW2 rows 64..95 (1.5 KB)
    __shared__ float   Bs[96];            // ib1 0..63, tb1 64..95 (384 B)

    const int t    = threadIdx.x;
    const int lane = t & 63;
    const int wv   = t >> 6;
    const int g    = lane >> 4;
    const int c    = lane & 15;
    const long long blockBase = (long long)blockIdx.x * 256;
    const long long base = blockBase + wv*64 + c;

    // ---------- cooperative staging (once per block) ------------------------
    #pragma unroll
    for (int s = t; s < 512; s += 256){
        int nt = s >> 7, ks = (s >> 6) & 1, ln = s & 63;
        int gg = ln >> 4, cc_ = ln & 15;
        float x[8];
        #pragma unroll
        for (int e = 0; e < 8; ++e){
            int k = ks*32 + 8*gg + e;
            x[e] = (k < 48) ? iW1[k*64 + nt*16 + cc_] : 0.f;
        }
        short8v h, l; split8(x, h, l);
        WimgH[nt][ks][ln] = h;
        WimgL[nt][ks][ln] = l;
    }
    if (t < 128){
        int nt = t >> 6, ln = t & 63;
        int gg = ln >> 4, cc_ = ln & 15;
        float x[8];
        #pragma unroll
        for (int e = 0; e < 8; ++e){
            int k = 8*gg + e;
            x[e] = (k < 16) ? tW1[k*32 + nt*16 + cc_] : 0.f;
        }
        short8v h, l; split8(x, h, l);
        WtxtH[nt][ln] = h;
        WtxtL[nt][ln] = l;
    }
    if (t < 96){
        W2s[t] = (t < 64) ? ((const float4*)iW2)[t] : ((const float4*)tW2)[t - 64];
        Bs[t]  = (t < 64) ? ib1[t] : tb1[t - 64];
    }
    __syncthreads();

    const float4 z = make_float4(0.f, 0.f, 0.f, 0.f);

    // ---------------- prologue: load tile 0 into cur ------------------------
    float4 c0, c1, c2, c3, c4, c5;
    {
        long long m = base; if (m >= B) m = B - 1;
        const float* irow = image + m*48;
        const float* trow = text  + m*16;
        c0 = *(const float4*)(irow + 8*g);
        c1 = *(const float4*)(irow + 8*g + 4);
        c2 = z; c3 = z; c4 = z; c5 = z;
        if (g < 2){
            c2 = *(const float4*)(irow + 32 + 8*g);
            c3 = *(const float4*)(irow + 36 + 8*g);
            c4 = *(const float4*)(trow + 8*g);
            c5 = *(const float4*)(trow + 8*g + 4);
        }
    }

    float4 n0 = z, n1 = z, n2 = z, n3 = z, n4 = z, n5 = z;

    // ---------------- main loop: 4 M-tiles, prefetch depth 1 ----------------
    #pragma unroll 1
    for (int ms = 0; ms < 4; ++ms){
        if (ms < 3){
            long long m = base + (ms + 1)*16; if (m >= B) m = B - 1;
            const float* irow = image + m*48;
            const float* trow = text  + m*16;
            n0 = *(const float4*)(irow + 8*g);
            n1 = *(const float4*)(irow + 8*g + 4);
            if (g < 2){
                n2 = *(const float4*)(irow + 32 + 8*g);
                n3 = *(const float4*)(irow + 36 + 8*g);
                n4 = *(const float4*)(trow + 8*g);
                n5 = *(const float4*)(trow + 8*g + 4);
            }
        }

        short8v A0h, A0l, A1h, A1l, ATh, ATl;
        pack8_cvt(c0, c1, A0h, A0l);
        pack8_cvt(c2, c3, A1h, A1l);
        pack8_cvt(c4, c5, ATh, ATl);

        f32x4 a0 = { 0.f, 0.f, 0.f, 0.f };
        f32x4 a1 = { 0.f, 0.f, 0.f, 0.f };
        f32x4 a2 = { 0.f, 0.f, 0.f, 0.f };
        f32x4 a3 = { 0.f, 0.f, 0.f, 0.f };
        f32x4 a4 = { 0.f, 0.f, 0.f, 0.f };
        f32x4 a5 = { 0.f, 0.f, 0.f, 0.f };

        // ---- phase 1: image k 0..31 ----
        { short8v bh = WimgH[0][0][lane], bl = WimgL[0][0][lane]; STEP3(a0, bh, bl, A0h, A0l) }
        { short8v bh = WimgH[1][0][lane], bl = WimgL[1][0][lane]; STEP3(a1, bh, bl, A0h, A0l) }
        { short8v bh = WimgH[2][0][lane], bl = WimgL[2][0][lane]; STEP3(a2, bh, bl, A0h, A0l) }
        { short8v bh = WimgH[3][0][lane], bl = WimgL[3][0][lane]; STEP3(a3, bh, bl, A0h, A0l) }
        __builtin_amdgcn_sched_barrier(0);

        // ---- phase 2: image k 32..47 (zero-padded to 64) ----
        { short8v bh = WimgH[0][1][lane], bl = WimgL[0][1][lane]; STEP3(a0, bh, bl, A1h, A1l) }
        { short8v bh = WimgH[1][1][lane], bl = WimgL[1][1][lane]; STEP3(a1, bh, bl, A1h, A1l) }
        { short8v bh = WimgH[2][1][lane], bl = WimgL[2][1][lane]; STEP3(a2, bh, bl, A1h, A1l) }
        { short8v bh = WimgH[3][1][lane], bl = WimgL[3][1][lane]; STEP3(a3, bh, bl, A1h, A1l) }
        __builtin_amdgcn_sched_barrier(0);

        // ---- phase 3: text k 0..15 (zero-padded to 32) ----
        { short8v bh = WtxtH[0][lane], bl = WtxtL[0][lane]; STEP3(a4, bh, bl, ATh, ATl) }
        { short8v bh = WtxtH[1][lane], bl = WtxtL[1][lane]; STEP3(a5, bh, bl, ATh, ATl) }

        // ---- epilogue: bias + relu + layer-2 (operands from LDS) -----------
        float po[4][4];
        #pragma unroll
        for (int r = 0; r < 4; ++r)
            #pragma unroll
            for (int o = 0; o < 4; ++o) po[r][o] = 0.f;

        { float4 w2 = W2s[c];      po_updateB(po, a0, w2, Bs[c]); }
        { float4 w2 = W2s[16+c];   po_updateB(po, a1, w2, Bs[16+c]); }
        { float4 w2 = W2s[32+c];   po_updateB(po, a2, w2, Bs[32+c]); }
        { float4 w2 = W2s[48+c];   po_updateB(po, a3, w2, Bs[48+c]); }
        { float4 w2 = W2s[64+c];   po_updateB(po, a4, w2, Bs[64+c]); }
        { float4 w2 = W2s[80+c];   po_updateB(po, a5, w2, Bs[80+c]); }

        reduce_po(po);                        // DPP rotation reduce (VALU only)
        if (c < 4){
            long long sIdx = blockBase + wv*64 + ms*16 + 4*g + c;
            if (sIdx < B)
                ((float4*)featsOut)[sIdx] = pick_row(po, c);
        }
        __builtin_amdgcn_sched_barrier(0);

        c0 = n0; c1 = n1; c2 = n2; c3 = n3; c4 = n4; c5 = n5;
    }
}

// ---------------------------------------------------------------------------
// Kernel 2b: quantum quadratic form + head, 1 thread/sample, lean registers.
// ---------------------------------------------------------------------------
__global__ __launch_bounds__(256, 8) void qnn_tail(
    const float* __restrict__ feats,
    const float* __restrict__ tb2, const float* __restrict__ ib2,
    const float* __restrict__ Aq,
    const float* __restrict__ cW1, const float* __restrict__ cb1,
    const float* __restrict__ cW2, const float* __restrict__ cb2,
    float* __restrict__ out, int B)
{
    __shared__ float As[256];
    const int t = threadIdx.x;
    As[t] = Aq[t];
    __syncthreads();

    long long samp = (long long)blockIdx.x * 256 + t;
    if (samp >= B) return;

    float4 f4 = ((const float4*)feats)[samp];
    float acc[4];
    acc[0] = tb2[0] + ib2[0] + f4.x;
    acc[1] = tb2[1] + ib2[1] + f4.y;
    acc[2] = tb2[2] + ib2[2] + f4.z;
    acc[3] = tb2[3] + ib2[3] + f4.w;

    float cth[4], sth[4];
    #pragma unroll
    for (int i = 0; i < 4; ++i){
        float f = acc[i] * 0.25f;
        __sincosf(f, &sth[i], &cth[i]);
    }
    float p01[4] = { cth[0]*cth[1], cth[0]*sth[1], sth[0]*cth[1], sth[0]*sth[1] };
    float p23[4] = { cth[2]*cth[3], cth[2]*sth[3], sth[2]*cth[3], sth[2]*sth[3] };
    float psi[16];
    #pragma unroll
    for (int x = 0; x < 4; ++x)
        #pragma unroll
        for (int y = 0; y < 4; ++y)
            psi[x*4+y] = p01[x] * p23[y];

    float q = 0.f;
    #pragma unroll
    for (int j = 0; j < 16; ++j){
        float row = 0.f;
        #pragma unroll
        for (int k = 0; k < 16; ++k) row = fmaf(As[j*16+k], psi[k], row);
        q = fmaf(psi[j], row, q);
    }

    float o0 = cb2[0], o1 = cb2[1];
    #pragma unroll
    for (int j = 0; j < 16; ++j){
        float h = fmaxf(fmaf(q, cW1[j], cb1[j]), 0.f);
        o0 = fmaf(h, cW2[j*2+0], o0);
        o1 = fmaf(h, cW2[j*2+1], o1);
    }
    float2* o2 = (float2*)out;
    o2[samp] = make_float2(o0, o1);
}

// ---------------------------------------------------------------------------
// Fallback: verified fused kernel (used only if workspace too small)
// ---------------------------------------------------------------------------
__global__ __launch_bounds__(256, 4) void qnn_fused(
    const float* __restrict__ text, const float* __restrict__ image,
    const float* __restrict__ tW1, const float* __restrict__ tb1,
    const float* __restrict__ tW2, const float* __restrict__ tb2,
    const float* __restrict__ iW1, const float* __restrict__ ib1,
    const float* __restrict__ iW2, const float* __restrict__ ib2,
    const float* __restrict__ A,
    const float* __restrict__ cW1, const float* __restrict__ cb1,
    const float* __restrict__ cW2, const float* __restrict__ cb2,
    float* __restrict__ out, int B)
{
    __shared__ short8v WimgH[4][2][64];
    __shared__ short8v WimgL[4][2][64];
    __shared__ short8v WtxtH[2][64];
    __shared__ short8v WtxtL[2][64];
    __shared__ float4  feats[256];

    const int t    = threadIdx.x;
    const int lane = t & 63;
    const int wv   = t >> 6;
    const int g    = lane >> 4;
    const int c    = lane & 15;
    const long long blockBase = (long long)blockIdx.x * 256;

    #pragma unroll
    for (int s = t; s < 512; s += 256){
        int nt = s >> 7, ks = (s >> 6) & 1, ln = s & 63;
        int gg = ln >> 4, cc_ = ln & 15;
        float x[8];
        #pragma unroll
        for (int e = 0; e < 8; ++e){
            int k = ks*32 + 8*gg + e;
            x[e] = (k < 48) ? iW1[k*64 + nt*16 + cc_] : 0.f;
        }
        short8v h, l; split8(x, h, l);
        WimgH[nt][ks][ln] = h;
        WimgL[nt][ks][ln] = l;
    }
    if (t < 128){
        int nt = t >> 6, ln = t & 63;
        int gg = ln >> 4, cc_ = ln & 15;
        float x[8];
        #pragma unroll
        for (int e = 0; e < 8; ++e){
            int k = 8*gg + e;
            x[e] = (k < 16) ? tW1[k*32 + nt*16 + cc_] : 0.f;
        }
        short8v h, l; split8(x, h, l);
        WtxtH[nt][ln] = h;
        WtxtL[nt][ln] = l;
    }
    __syncthreads();

    const float bI0 = ib1[c],      bI1 = ib1[16 + c];
    const float bI2 = ib1[32 + c], bI3 = ib1[48 + c];
    const float bT0 = tb1[c],      bT1 = tb1[16 + c];

    #pragma unroll 1
    for (int ms = 0; ms < 4; ++ms){
        long long m = blockBase + wv*64 + ms*16 + c;
        if (m >= B) m = B - 1;
        const float* irow = image + m*48;
        const float* trow = text  + m*16;

        const float4 z = make_float4(0.f, 0.f, 0.f, 0.f);
        float4 i0a = *(const float4*)(irow + 8*g);
        float4 i0b = *(const float4*)(irow + 8*g + 4);
        float4 i1a = z, i1b = z, t0a = z, t0b = z;
        if (g < 2){
            i1a = *(const float4*)(irow + 32 + 8*g);
            i1b = *(const float4*)(irow + 36 + 8*g);
            t0a = *(const float4*)(trow + 8*g);
            t0b = *(const float4*)(trow + 8*g + 4);
        }

        f32x4 a0 = { bI0, bI0, bI0, bI0 };
        f32x4 a1 = { bI1, bI1, bI1, bI1 };
        f32x4 a2 = { bI2, bI2, bI2, bI2 };
        f32x4 a3 = { bI3, bI3, bI3, bI3 };
        f32x4 a4 = { bT0, bT0, bT0, bT0 };
        f32x4 a5 = { bT1, bT1, bT1, bT1 };

        short8v Ah, Al;

        pack8(i0a, i0b, Ah, Al);
        { short8v bh = WimgH[0][0][lane], bl = WimgL[0][0][lane]; STEP3(a0, bh, bl, Ah, Al) }
        { short8v bh = WimgH[1][0][lane], bl = WimgL[1][0][lane]; STEP3(a1, bh, bl, Ah, Al) }
        { short8v bh = WimgH[2][0][lane], bl = WimgL[2][0][lane]; STEP3(a2, bh, bl, Ah, Al) }
        { short8v bh = WimgH[3][0][lane], bl = WimgL[3][0][lane]; STEP3(a3, bh, bl, Ah, Al) }
        __builtin_amdgcn_sched_barrier(0);

        pack8(i1a, i1b, Ah, Al);
        { short8v bh = WimgH[0][1][lane], bl = WimgL[0][1][lane]; STEP3(a0, bh, bl, Ah, Al) }
        { short8v bh = WimgH[1][1][lane], bl = WimgL[1][1][lane]; STEP3(a1, bh, bl, Ah, Al) }
        { short8v bh = WimgH[2][1][lane], bl = WimgL[2][1][lane]; STEP3(a2, bh, bl, Ah, Al) }
        { short8v bh = WimgH[3][1][lane], bl = WimgL[3][1][lane]; STEP3(a3, bh, bl, Ah, Al) }
        __builtin_amdgcn_sched_barrier(0);

        pack8(t0a, t0b, Ah, Al);
        { short8v bh = WtxtH[0][lane], bl = WtxtL[0][lane]; STEP3(a4, bh, bl, Ah, Al) }
        { short8v bh = WtxtH[1][lane], bl = WtxtL[1][lane]; STEP3(a5, bh, bl, Ah, Al) }
        __builtin_amdgcn_sched_barrier(0);

        float po[4][4];
        #pragma unroll
        for (int r = 0; r < 4; ++r)
            #pragma unroll
            for (int o = 0; o < 4; ++o) po[r][o] = 0.f;

        { float4 w2 = *(const float4*)(iW2 + (c)*4);      po_update(po, a0, w2); }
        { float4 w2 = *(const float4*)(iW2 + (16+c)*4);   po_update(po, a1, w2); }
        { float4 w2 = *(const float4*)(iW2 + (32+c)*4);   po_update(po, a2, w2); }
        { float4 w2 = *(const float4*)(iW2 + (48+c)*4);   po_update(po, a3, w2); }
        { float4 w2 = *(const float4*)(tW2 + (c)*4);      po_update(po, a4, w2); }
        { float4 w2 = *(const float4*)(tW2 + (16+c)*4);   po_update(po, a5, w2); }

        reduce_po(po);
        if (c < 4)
            feats[wv*64 + ms*16 + 4*g + c] = pick_row(po, c);
        __builtin_amdgcn_sched_barrier(0);
    }

    __syncthreads();

    long long samp = blockBase + t;
    if (samp < B){
        float4 f4 = feats[t];
        float acc[4];
        acc[0] = tb2[0] + ib2[0] + f4.x;
        acc[1] = tb2[1] + ib2[1] + f4.y;
        acc[2] = tb2[2] + ib2[2] + f4.z;
        acc[3] = tb2[3] + ib2[3] + f4.w;

        float cth[4], sth[4];
        #pragma unroll
        for (int i = 0; i < 4; ++i){
            float f = acc[i] * 0.25f;
            __sincosf(f, &sth[i], &cth[i]);
        }
        float p01[4] = { cth[0]*cth[1], cth[0]*sth[1], sth[0]*cth[1], sth[0]*sth[1] };
        float p23[4] = { cth[2]*cth[3], cth[2]*sth[3], sth[2]*cth[3], sth[2]*sth[3] };
        float psi[16];
        #pragma unroll
        for (int x = 0; x < 4; ++x)
            #pragma unroll
            for (int y = 0; y < 4; ++y)
                psi[x*4+y] = p01[x] * p23[y];

        float q = 0.f;
        #pragma unroll
        for (int j = 0; j < 16; ++j){
            float row = 0.f;
            #pragma unroll
            for (int k = 0; k < 16; ++k) row = fmaf(A[j*16+k], psi[k], row);
            q = fmaf(psi[j], row, q);
        }

        float o0 = cb2[0], o1 = cb2[1];
        #pragma unroll
        for (int j = 0; j < 16; ++j){
            float h = fmaxf(fmaf(q, cW1[j], cb1[j]), 0.f);
            o0 = fmaf(h, cW2[j*2+0], o0);
            o1 = fmaf(h, cW2[j*2+1], o1);
        }
        float2* o2 = (float2*)out;
        o2[samp] = make_float2(o0, o1);
    }
}

extern "C" void kernel_launch(void* const* d_in, const int* in_sizes, int n_in,
                              void* d_out, int out_size, void* d_ws, size_t ws_size,
                              hipStream_t stream)
{
    const float* text  = (const float*)d_in[0];
    const float* image = (const float*)d_in[1];
    const float* tW1   = (const float*)d_in[2];
    const float* tb1   = (const float*)d_in[3];
    const float* tW2   = (const float*)d_in[4];
    const float* tb2   = (const float*)d_in[5];
    const float* iW1   = (const float*)d_in[6];
    const float* ib1   = (const float*)d_in[7];
    const float* iW2   = (const float*)d_in[8];
    const float* ib2   = (const float*)d_in[9];
    const float* qw    = (const float*)d_in[10];
    const float* cW1   = (const float*)d_in[11];
    const float* cb1   = (const float*)d_in[12];
    const float* cW2   = (const float*)d_in[13];
    const float* cb2   = (const float*)d_in[14];

    float* A = (float*)d_ws;          // 256 floats
    int B = in_sizes[0] / 16;

    qnn_precompute_A<<<1, 256, 0, stream>>>(qw, A);

    int block = 256;
    int grid = (B + block - 1) / block;
    size_t need = 1024 + (size_t)B * 16;   // A (1 KB) + feats (B x float4)

    if (ws_size >= need){
        float* featsWs = (float*)((char*)d_ws + 1024);
        qnn_feats<<<grid, block, 0, stream>>>(
            text, image, tW1, tb1, tW2, iW1, ib1, iW2, featsWs, B);
        qnn_tail<<<grid, block, 0, stream>>>(
            featsWs, tb2, ib2, A, cW1, cb1, cW2, cb2, (float*)d_out, B);
    } else {
        qnn_fused<<<grid, block, 0, stream>>>(
            text, image, tW1, tb1, tW2, tb2, iW1, ib1, iW2, ib2,
            A, cW1, cb1, cW2, cb2, (float*)d_out, B);
    }
}